// Round 9
// baseline (1749.084 us; speedup 1.0000x reference)
//
#include <hip/hip_runtime.h>
#include <math.h>

#define NN 16000
#define EE 256000
#define GG 64
#define KK 10
#define CC 32
#define NBB 8
#define MHH 16
#define NPP 4
#define NEE 3
#define NDD 6
#define SHH 9
#define RHH 64
#define SHCC (SHH*CC)   // 288
#define NBLKN 260
#define NPADN (NBLKN*64)

typedef __attribute__((ext_vector_type(8))) short s8b;    // bf16 frag (4 VGPR)
typedef __attribute__((ext_vector_type(4))) float f32x4;  // acc frag

__device__ __forceinline__ float siluf(float x){ return x / (1.0f + __expf(-x)); }
__device__ __forceinline__ short bf16rne(float x){
  unsigned u = __float_as_uint(x);
  unsigned r = u + 0x7FFFu + ((u>>16)&1u);
  return (short)(r>>16);
}

// ---------------- init: kidx, feats0, e0, up(l=0), khist ----------------
__global__ __launch_bounds__(256) void init_kernel(
    const float* __restrict__ attrs, const float* __restrict__ E0v,
    const float* __restrict__ Wemb, const float* __restrict__ Wup0,
    const int* __restrict__ batch,
    int* __restrict__ kidx, float* __restrict__ feats, float* __restrict__ e0g,
    float* __restrict__ up, int* __restrict__ khist)
{
  int t = blockIdx.x*blockDim.x + threadIdx.x;
  if (t >= NN*CC) return;
  int n = t >> 5, d = t & 31;
  const float* a = attrs + n*KK;
  int k = 0; float best = a[0];
  #pragma unroll
  for (int j=1;j<KK;j++){ float v=a[j]; if (v>best){best=v;k=j;} }
  float* f = feats + n*SHCC;
  f[d] = Wemb[k*CC+d];
  #pragma unroll
  for (int s=1;s<SHH;s++) f[s*CC+d] = 0.0f;
  float accu = 0.0f;
  #pragma unroll
  for (int c=0;c<CC;c++) accu += Wemb[k*CC+c]*Wup0[c*CC+d];
  up[n*CC+d] = accu * 0.0625f;
  if (d==0){
    kidx[n]=k;
    atomicAdd(&e0g[batch[n]], E0v[k]);
    atomicAdd(&khist[k], 1);
  }
}

// ---------------- counting sort of edges by dst ----------------
__global__ __launch_bounds__(256) void hist_kernel(
    const int* __restrict__ ei, int* __restrict__ rowptr)
{
  int e = blockIdx.x*256 + threadIdx.x;
  if (e < EE) atomicAdd(&rowptr[ei[EE+e]+1], 1);
}

__global__ __launch_bounds__(1024) void scan_kernel(
    int* __restrict__ rowptr, int* __restrict__ cursor)
{
  __shared__ int part[1024];
  const int t = threadIdx.x;
  const int SEG = 16;
  const int base = t*SEG;
  int a[SEG];
  int run = 0;
  #pragma unroll
  for (int i=0;i<SEG;i++){
    int idx = base+i;
    int v = (idx <= NN) ? rowptr[idx] : 0;
    run += v; a[i] = run;
  }
  part[t] = run;
  __syncthreads();
  for (int off=1; off<1024; off<<=1){
    int v = (t>=off) ? part[t-off] : 0;
    __syncthreads();
    part[t] += v;
    __syncthreads();
  }
  int offset = (t>0) ? part[t-1] : 0;
  #pragma unroll
  for (int i=0;i<SEG;i++){
    int idx = base+i;
    if (idx <= NN){
      int val = offset + a[i];
      rowptr[idx] = val;
      if (idx < NN) cursor[idx] = val;
    }
  }
}

__global__ __launch_bounds__(256) void scatter_kernel(
    const int* __restrict__ ei, int* __restrict__ cursor, int* __restrict__ sorted)
{
  int e = blockIdx.x*256 + threadIdx.x;
  if (e < EE){
    int d = ei[EE+e];
    int p = atomicAdd(&cursor[d], 1);
    sorted[p] = e;
  }
}

// ---------------- node k-sort: 64-aligned segments per species ----------------
__global__ void kscan_kernel(const int* __restrict__ khist, int* __restrict__ kcursor)
{
  if (threadIdx.x==0 && blockIdx.x==0){
    int off=0;
    for (int k=0;k<KK;k++){
      kcursor[k]=off;
      off += ((khist[k]+63)>>6)<<6;
    }
  }
}

__global__ __launch_bounds__(256) void kscatter_kernel(
    const int* __restrict__ kidx, int* __restrict__ kcursor, int* __restrict__ nsorted)
{
  int n = blockIdx.x*256 + threadIdx.x;
  if (n < NN){
    int p = atomicAdd(&kcursor[kidx[n]], 1);
    nsorted[p] = n;
  }
}

// ---------------- fused MFMA edge kernel: block-cooperative 64-edge windows ----------------
__global__ __launch_bounds__(256, 2) void edge_kernel(
    const float* __restrict__ pos, const float* __restrict__ shifts,
    const float* __restrict__ Wr1, const float* __restrict__ Wr2,
    const float* __restrict__ Wr3, const float* __restrict__ up,
    const int* __restrict__ ei, const int* __restrict__ sorted,
    float* __restrict__ agg)
{
  __shared__ alignas(16) short sW3T[SHCC*RHH];      // 36864 B
  __shared__ alignas(16) short sW2T[RHH*RHH];       // 8192 B
  __shared__ alignas(16) float sW1T[RHH*NBB];       // 2048 B
  __shared__ alignas(16) char  uni[64*65*4];        // 16640 B: msg | {ef, h2s}
  __shared__ alignas(16) float sh_l[4][16*12];      // 3072 B
  __shared__ int dst_l[64];                         // 256 B

  for (int i=threadIdx.x; i<RHH*SHCC; i+=256){
    int kk = i/SHCC, o = i - kk*SHCC;
    sW3T[(o*RHH + kk) ^ ((o&7)<<3)] = bf16rne(Wr3[i]);
  }
  for (int i=threadIdx.x; i<RHH*RHH; i+=256){
    int k = i>>6, kk = i&63;
    sW2T[(kk*RHH + k) ^ ((kk&7)<<3)] = bf16rne(Wr2[i]);
  }
  for (int i=threadIdx.x; i<NBB*RHH; i+=256){
    int b = i>>6, k = i&63;
    sW1T[k*NBB + b] = Wr1[i];
  }
  __syncthreads();

  const int tid  = threadIdx.x;
  const int lane = tid & 63;
  const int el   = lane & 15;
  const int r    = lane >> 4;
  const int wv   = tid >> 6;
  float* msg = (float*)uni;
  float* efw = (float*)(uni + wv*512);
  short* h2w = (short*)(uni + 2048 + wv*2304);
  float* shw = sh_l[wv];
  const f32x4 zf = {0.f,0.f,0.f,0.f};
  const float PI_ = 3.14159265358979323846f;

  for (int w = blockIdx.x; w < EE/64; w += gridDim.x) {
    const int e0 = w*64 + wv*16;
    {
      const int e = sorted[e0 + el];
      const int src = ei[e], dst = ei[EE+e];
      if (r==0) dst_l[wv*16+el] = dst;
      float x = pos[src*3+0]-pos[dst*3+0]+shifts[e*3+0];
      float y = pos[src*3+1]-pos[dst*3+1]+shifts[e*3+1];
      float z = pos[src*3+2]-pos[dst*3+2]+shifts[e*3+2];
      float rr = sqrtf(x*x+y*y+z*z+1e-12f);
      float ir = 1.0f/rr;
      x*=ir; y*=ir; z*=ir;
      const float S3=1.7320508075688772f, S5h=1.1180339887498949f;
      const float S15=3.872983346207417f, S15h=1.9364916731037085f;
      if (r==0){ shw[el*12+0]=1.0f;            shw[el*12+1]=S3*x;     shw[el*12+2]=S3*y; }
      else if (r==1){ shw[el*12+3]=S3*z;       shw[el*12+4]=S15*x*y;  shw[el*12+5]=S15*y*z; }
      else if (r==2){ shw[el*12+6]=S5h*(3.0f*z*z-1.0f); shw[el*12+7]=S15*x*z; shw[el*12+8]=S15h*(x*x-y*y); }
      float u = rr*0.2f;
      float u2=u*u, u3=u2*u, u6=u3*u3;
      float env = 1.0f - 28.0f*u6 + 48.0f*u6*u - 21.0f*u6*u2;
      env = (u<1.0f)? env : 0.0f;
      env *= ir * 0.6324555320336759f;
      float n1 = (float)(r+1), n2 = (float)(r+5);
      efw[el*8 + r]     = __sinf(n1*PI_*u)*env;
      efw[el*8 + r + 4] = __sinf(n2*PI_*u)*env;
    }
    float h1v[16];
    {
      f32x4 efa = *(const f32x4*)&efw[el*8];
      f32x4 efb = *(const f32x4*)&efw[el*8+4];
      #pragma unroll
      for (int s=0;s<2;s++){
        #pragma unroll
        for (int j=0;j<8;j++){
          int kq = 32*s + 8*r + j;
          f32x4 wa = *(const f32x4*)&sW1T[kq*NBB];
          f32x4 wb = *(const f32x4*)&sW1T[kq*NBB+4];
          float acc = efa[0]*wa[0]+efa[1]*wa[1]+efa[2]*wa[2]+efa[3]*wa[3]
                    + efb[0]*wb[0]+efb[1]*wb[1]+efb[2]*wb[2]+efb[3]*wb[3];
          h1v[s*8+j] = siluf(acc);
        }
      }
    }
    s8b a1s0, a1s1;
    #pragma unroll
    for (int j=0;j<8;j++){ a1s0[j]=bf16rne(h1v[j]); a1s1[j]=bf16rne(h1v[8+j]); }

    f32x4 aw2[4];
    #pragma unroll
    for (int t=0;t<4;t++){
      int kk = 16*t + el;
      int sw = (kk&7)<<3;
      s8b b0 = *(const s8b*)&sW2T[(kk*RHH + 8*r     ) ^ sw];
      s8b b1 = *(const s8b*)&sW2T[(kk*RHH + 8*r + 32) ^ sw];
      f32x4 acc = __builtin_amdgcn_mfma_f32_16x16x32_bf16(a1s0, b0, zf, 0,0,0);
      aw2[t]    = __builtin_amdgcn_mfma_f32_16x16x32_bf16(a1s1, b1, acc, 0,0,0);
    }
    #pragma unroll
    for (int t=0;t<4;t++){
      #pragma unroll
      for (int reg=0;reg<4;reg++)
        h2w[(4*r+reg)*72 + 16*t + el] = bf16rne(siluf(aw2[t][reg]));
    }
    s8b a2s0 = *(const s8b*)&h2w[el*72 + 8*r];
    s8b a2s1 = *(const s8b*)&h2w[el*72 + 32 + 8*r];

    float upv[4][2];
    #pragma unroll
    for (int reg=0;reg<4;reg++){
      int ee = sorted[e0 + 4*r + reg];
      int s_ = ei[ee];
      upv[reg][0] = up[s_*CC + el];
      upv[reg][1] = up[s_*CC + 16 + el];
    }
    __syncthreads();

    unsigned long long runmask;
    {
      bool flag = (lane==0) || (dst_l[lane] != dst_l[lane-1]);
      runmask = __ballot(flag);
    }

    #pragma unroll
    for (int c=0;c<5;c++){
      const int tBeg = 4*c;
      const int tEnd = (c<4)? (tBeg+4) : 18;
      for (int t=tBeg;t<tEnd;t++){
        int o = 16*t + el;
        int sw = (o&7)<<3;
        s8b b0 = *(const s8b*)&sW3T[(o*RHH + 8*r     ) ^ sw];
        s8b b1 = *(const s8b*)&sW3T[(o*RHH + 8*r + 32) ^ sw];
        f32x4 acc = __builtin_amdgcn_mfma_f32_16x16x32_bf16(a2s0, b0, zf, 0,0,0);
        acc       = __builtin_amdgcn_mfma_f32_16x16x32_bf16(a2s1, b1, acc, 0,0,0);
        const int sidx = t>>1, spar = t&1;
        #pragma unroll
        for (int reg=0;reg<4;reg++){
          float v = acc[reg] * shw[(4*r+reg)*12 + sidx] * upv[reg][spar];
          msg[(wv*16 + 4*r + reg)*65 + 16*(t-tBeg) + el] = v;
        }
      }
      __syncthreads();
      {
        const int col = (c<4) ? (tid & 63) : (tid & 31);
        const bool act = (c<4) || ((tid & 63) < 32);
        const int q = tid >> 6;
        const int obase = 64*c;
        if (act){
          unsigned long long m = runmask;
          int j = 0;
          while (m){
            int s = __builtin_ctzll(m);
            m &= (m-1);
            int en = m ? __builtin_ctzll(m) : 64;
            if ((j & 3) == q){
              float a = 0.0f;
              for (int i=s;i<en;i++) a += msg[i*65 + col];
              atomicAdd(agg + (size_t)dst_l[s]*SHCC + obase + col, a);
            }
            j++;
          }
        }
      }
      __syncthreads();
    }
  }
}

// ---------------- node v3: k-sorted 16-node blocks, register-resident weight columns ----------------
// Thread (nn,d) owns nodes j1=nn, j2=nn+8 of its block; weight column d of each
// matrix is loaded ONCE per lv-group into VGPRs and reused across s-channels and
// both nodes. All cross-lane LDS traffic stays within one 32-lane group -> no barriers.
__global__ __launch_bounds__(256, 4) void node_kernel(
    const float* __restrict__ feats, float* __restrict__ fout,
    const float* __restrict__ agg,
    const int* __restrict__ nsorted, const int* __restrict__ kidx,
    const int* __restrict__ batch,
    const float* __restrict__ Wsc, const float* __restrict__ Wprod,
    const float* __restrict__ WcL,
    const float* __restrict__ We1, const float* __restrict__ We2,
    const float* __restrict__ Wi1, const float* __restrict__ Wi2,
    const float* __restrict__ Wdp, const float* __restrict__ Wup1,
    float* __restrict__ up,
    float* __restrict__ eng, float* __restrict__ inv, float* __restrict__ dip)
{
  __shared__ float s0l[16][CC];
  __shared__ float sul[16][CC];
  __shared__ float vl[16][3][CC];
  __shared__ float hl[16][CC];

  const int base = blockIdx.x*16;
  const int n0 = nsorted[base];
  if (n0 < 0) return;                      // all-padding block (padding is suffix)
  const int kb = kidx[n0];
  const int t = threadIdx.x, nn = t>>5, d = t&31;
  const int n1 = nsorted[base+nn], n2 = nsorted[base+8+nn];
  const int m1 = (n1>=0)? n1 : n0;         // safe dummies for loads
  const int m2 = (n2>=0)? n2 : n0;

  const float* ag1 = agg   + (size_t)m1*SHCC;
  const float* ft1 = feats + (size_t)m1*SHCC;
  const float* ag2 = agg   + (size_t)m2*SHCC;
  const float* ft2 = feats + (size_t)m2*SHCC;

  float nw1[SHH], nw2[SHH];
  float wp[CC], ws[CC];

  #pragma unroll
  for (int lv=0; lv<3; ++lv){
    #pragma unroll
    for (int c=0;c<CC;c++){
      wp[c] = Wprod[lv*CC*CC + c*CC + d];
      ws[c] = Wsc[((size_t)(kb*3+lv))*CC*CC + c*CC + d];
    }
    const int sbeg = (lv==0)?0:((lv==1)?1:4);
    const int send = (lv==0)?1:((lv==1)?4:9);
    #pragma unroll
    for (int s=sbeg;s<send;s++){
      float acc1=0.0f, acc2=0.0f;
      #pragma unroll
      for (int q=0;q<8;q++){
        f32x4 a1 = *(const f32x4*)&ag1[s*CC + q*4];
        f32x4 f1 = *(const f32x4*)&ft1[s*CC + q*4];
        f32x4 a2 = *(const f32x4*)&ag2[s*CC + q*4];
        f32x4 f2 = *(const f32x4*)&ft2[s*CC + q*4];
        #pragma unroll
        for (int j=0;j<4;j++){
          const int c = q*4+j;
          acc1 += a1[j]*wp[c] + f1[j]*ws[c];
          acc2 += a2[j]*wp[c] + f2[j]*ws[c];
        }
      }
      nw1[s]=acc1; nw2[s]=acc2;
    }
  }

  // stage s0 and vector channels (intra-32-lane-group communication only)
  s0l[nn][d]   = nw1[0];  s0l[nn+8][d]   = nw2[0];
  vl[nn][0][d] = nw1[1];  vl[nn+8][0][d] = nw2[1];
  vl[nn][1][d] = nw1[2];  vl[nn+8][1][d] = nw2[2];
  vl[nn][2][d] = nw1[3];  vl[nn+8][2][d] = nw2[3];

  // channel-wise cubic correction via register-resident Wc columns
  float corr1=0.0f, corr2=0.0f;
  #pragma unroll
  for (int pw=0; pw<3; pw++){
    #pragma unroll
    for (int c=0;c<CC;c++) wp[c] = WcL[((size_t)(pw*KK+kb))*CC*CC + c*CC + d];
    #pragma unroll
    for (int c=0;c<CC;c++){
      float s01 = s0l[nn][c],  s02 = s0l[nn+8][c];
      float p1 = (pw==0)? s01 : ((pw==1)? s01*s01 : s01*s01*s01);
      float p2 = (pw==0)? s02 : ((pw==1)? s02*s02 : s02*s02*s02);
      corr1 += p1*wp[c]; corr2 += p2*wp[c];
    }
  }
  float su1 = nw1[0] + corr1;
  float su2 = nw2[0] + corr2;
  sul[nn][d] = su1; sul[nn+8][d] = su2;

  if (n1>=0){
    float* fo = fout + (size_t)n1*SHCC;
    fo[d] = su1;
    #pragma unroll
    for (int s=1;s<SHH;s++) fo[s*CC+d] = nw1[s];
  }
  if (n2>=0){
    float* fo = fout + (size_t)n2*SHCC;
    fo[d] = su2;
    #pragma unroll
    for (int s=1;s<SHH;s++) fo[s*CC+d] = nw2[s];
  }

  // readout hidden layers (m = d&15; lanes 0-15 -> We1, 16-31 -> Wi1)
  {
    const int m = d & 15;
    const float* W = (d < MHH) ? We1 : Wi1;
    float a1=0.0f, a2=0.0f;
    #pragma unroll
    for (int c=0;c<CC;c++){
      float w = W[c*MHH+m];
      a1 += sul[nn][c]*w; a2 += sul[nn+8][c]*w;
    }
    hl[nn][d] = siluf(a1); hl[nn+8][d] = siluf(a2);
  }
  // up for next layer
  {
    #pragma unroll
    for (int c=0;c<CC;c++) wp[c] = Wup1[c*CC+d];
    float a1=0.0f, a2=0.0f;
    #pragma unroll
    for (int c=0;c<CC;c++){ a1 += sul[nn][c]*wp[c]; a2 += sul[nn+8][c]*wp[c]; }
    if (n1>=0) up[n1*CC+d] = a1 * 0.0625f;
    if (n2>=0) up[n2*CC+d] = a2 * 0.0625f;
  }
  // graph-level readouts (one atomic per node per output element)
  #pragma unroll
  for (int h=0; h<2; ++h){
    const int nj = h ? n2 : n1;
    const int jr = h ? nn+8 : nn;
    if (nj < 0) continue;
    const int b = batch[nj];
    if (d < NEE){
      float acc=0.0f;
      #pragma unroll
      for (int m=0;m<MHH;m++) acc += hl[jr][m]*We2[m*NEE+d];
      atomicAdd(&eng[b*NEE+d], acc);
    } else if (d < NEE+NPP){
      const int pp = d-NEE;
      float acc=0.0f;
      #pragma unroll
      for (int m=0;m<MHH;m++) acc += hl[jr][MHH+m]*Wi2[m*NPP+pp];
      atomicAdd(&inv[b*NPP+pp], acc);
    } else if (d < 7+3*NDD){
      const int idx = d-7;
      const int v = idx/NDD;
      const int dd = idx - v*NDD;
      float acc=0.0f;
      #pragma unroll
      for (int c=0;c<CC;c++) acc += vl[jr][v][c]*Wdp[c*NDD+dd];
      atomicAdd(&dip[(b*3+v)*NDD+dd], acc);
    }
  }
}

// ---------------- final decode ----------------
__global__ __launch_bounds__(64) void final_kernel(
    const float* __restrict__ eng, const float* __restrict__ inv,
    const float* __restrict__ dip, const float* __restrict__ e0g,
    const float* __restrict__ Wd1, const float* __restrict__ bd1,
    const float* __restrict__ Wd2, const float* __restrict__ bd2,
    float* __restrict__ out)
{
  const int g = threadIdx.x;
  if (g >= GG) return;
  float e0 = e0g[g];
  float iv0=inv[g*NPP+0], iv1=inv[g*NPP+1], iv2=inv[g*NPP+2], iv3=inv[g*NPP+3];
  float o0=bd2[0], o1=bd2[1], o2=bd2[2];
  for (int m=0;m<RHH;m++){
    float hm = bd1[m] + iv0*Wd1[0*RHH+m] + iv1*Wd1[1*RHH+m] + iv2*Wd1[2*RHH+m] + iv3*Wd1[3*RHH+m];
    hm = siluf(hm);
    o0 += hm*Wd2[m*NEE+0]; o1 += hm*Wd2[m*NEE+1]; o2 += hm*Wd2[m*NEE+2];
  }
  float* og = out + g*24;
  og[0]=o0+e0; og[1]=o1+e0; og[2]=o2+e0;
  og[3]=eng[g*NEE+0]+e0; og[4]=eng[g*NEE+1]+e0; og[5]=eng[g*NEE+2]+e0;
  for (int dd=0;dd<NDD;dd++)
    for (int v=0;v<3;v++)
      og[6+dd*3+v] = dip[(g*3+v)*NDD+dd];
}

extern "C" void kernel_launch(void* const* d_in, const int* in_sizes, int n_in,
                              void* d_out, int out_size, void* d_ws, size_t ws_size,
                              hipStream_t stream)
{
  const float* pos    = (const float*)d_in[0];
  const float* attrs  = (const float*)d_in[1];
  const float* shifts = (const float*)d_in[2];
  const float* E0v    = (const float*)d_in[3];
  const float* Wemb   = (const float*)d_in[4];
  const float* Wup    = (const float*)d_in[5];
  const float* Wr1    = (const float*)d_in[6];
  const float* Wr2    = (const float*)d_in[7];
  const float* Wr3    = (const float*)d_in[8];
  const float* Wsc    = (const float*)d_in[9];
  const float* Wprod  = (const float*)d_in[10];
  const float* Wc     = (const float*)d_in[11];
  const float* We1    = (const float*)d_in[12];
  const float* We2    = (const float*)d_in[13];
  const float* Wi1    = (const float*)d_in[14];
  const float* Wi2    = (const float*)d_in[15];
  const float* Wdp    = (const float*)d_in[16];
  const float* Wd1    = (const float*)d_in[17];
  const float* bd1    = (const float*)d_in[18];
  const float* Wd2    = (const float*)d_in[19];
  const float* bd2    = (const float*)d_in[20];
  const int*   ei     = (const int*)d_in[21];
  const int*   batch  = (const int*)d_in[22];
  float* out = (float*)d_out;

  float* feats = (float*)d_ws;                 // N*288
  float* agg   = feats + (size_t)NN*SHCC;      // N*288
  float* up    = agg   + (size_t)NN*SHCC;      // N*32
  float* accum = up    + (size_t)NN*CC;        // 1664 floats + khist
  float* e0g = accum;          // 64
  float* eng = accum + 64;     // 64*3
  float* inv = accum + 256;    // 64*4
  float* dip = accum + 512;    // 64*18
  int*   khist   = (int*)(accum + 1664);       // 16
  int*   kcursor = khist + 16;                 // 16
  int*   kidx    = kcursor + 16;               // NN
  int*   rowptr  = kidx + NN;                  // NN+1
  int*   cursor  = rowptr + NN + 1;            // NN
  int*   sorted  = cursor + NN;                // EE
  int*   nsorted = sorted + EE;                // NPADN

  hipMemsetAsync(accum, 0, (1664+16)*sizeof(float), stream);
  hipMemsetAsync(rowptr, 0, (NN+1)*sizeof(int), stream);
  hipMemsetAsync(nsorted, 0xFF, NPADN*sizeof(int), stream);
  init_kernel<<<(NN*CC)/256, 256, 0, stream>>>(attrs, E0v, Wemb, Wup, batch, kidx, feats, e0g, up, khist);
  hist_kernel<<<EE/256, 256, 0, stream>>>(ei, rowptr);
  scan_kernel<<<1, 1024, 0, stream>>>(rowptr, cursor);
  scatter_kernel<<<EE/256, 256, 0, stream>>>(ei, cursor, sorted);
  kscan_kernel<<<1, 64, 0, stream>>>(khist, kcursor);
  kscatter_kernel<<<(NN+255)/256, 256, 0, stream>>>(kidx, kcursor, nsorted);

  for (int l=0; l<2; ++l){
    hipMemsetAsync(agg, 0, (size_t)NN*SHCC*sizeof(float), stream);
    edge_kernel<<<512, 256, 0, stream>>>(pos, shifts,
        Wr1 + l*NBB*RHH, Wr2 + l*RHH*RHH, Wr3 + l*RHH*SHCC,
        up, ei, sorted, agg);
    node_kernel<<<NPADN/16, 256, 0, stream>>>(feats, feats, agg, nsorted, kidx, batch,
        Wsc + l*KK*3*CC*CC, Wprod + l*3*CC*CC, Wc + l*3*KK*CC*CC,
        We1 + l*CC*MHH, We2 + l*MHH*NEE, Wi1 + l*CC*MHH, Wi2 + l*MHH*NPP,
        Wdp + l*CC*NDD, Wup + 1*CC*CC, up,
        eng, inv, dip);
  }
  final_kernel<<<1, 64, 0, stream>>>(eng, inv, dip, e0g, Wd1, bd1, Wd2, bd2, out);
}

// Round 10
// 901.986 us; speedup vs baseline: 1.9391x; 1.9391x over previous
//
#include <hip/hip_runtime.h>
#include <math.h>

#define NN 16000
#define EE 256000
#define GG 64
#define KK 10
#define CC 32
#define NBB 8
#define MHH 16
#define NPP 4
#define NEE 3
#define NDD 6
#define SHH 9
#define RHH 64
#define SHCC (SHH*CC)   // 288
#define NBLKN 260
#define NPADN (NBLKN*64)

typedef __attribute__((ext_vector_type(8))) short s8b;    // bf16 frag (4 VGPR)
typedef __attribute__((ext_vector_type(4))) float f32x4;  // acc frag

__device__ __forceinline__ float siluf(float x){ return x / (1.0f + __expf(-x)); }
__device__ __forceinline__ short bf16rne(float x){
  unsigned u = __float_as_uint(x);
  unsigned r = u + 0x7FFFu + ((u>>16)&1u);
  return (short)(r>>16);
}

// ---------------- init: kidx, feats0, e0, up(l=0), khist ----------------
__global__ __launch_bounds__(256) void init_kernel(
    const float* __restrict__ attrs, const float* __restrict__ E0v,
    const float* __restrict__ Wemb, const float* __restrict__ Wup0,
    const int* __restrict__ batch,
    int* __restrict__ kidx, float* __restrict__ feats, float* __restrict__ e0g,
    float* __restrict__ up, int* __restrict__ khist)
{
  int t = blockIdx.x*blockDim.x + threadIdx.x;
  if (t >= NN*CC) return;
  int n = t >> 5, d = t & 31;
  const float* a = attrs + n*KK;
  int k = 0; float best = a[0];
  #pragma unroll
  for (int j=1;j<KK;j++){ float v=a[j]; if (v>best){best=v;k=j;} }
  float* f = feats + n*SHCC;
  f[d] = Wemb[k*CC+d];
  #pragma unroll
  for (int s=1;s<SHH;s++) f[s*CC+d] = 0.0f;
  float accu = 0.0f;
  #pragma unroll
  for (int c=0;c<CC;c++) accu += Wemb[k*CC+c]*Wup0[c*CC+d];
  up[n*CC+d] = accu * 0.0625f;
  if (d==0){
    kidx[n]=k;
    atomicAdd(&e0g[batch[n]], E0v[k]);
    atomicAdd(&khist[k], 1);
  }
}

// ---------------- counting sort of edges by dst ----------------
__global__ __launch_bounds__(256) void hist_kernel(
    const int* __restrict__ ei, int* __restrict__ rowptr)
{
  int e = blockIdx.x*256 + threadIdx.x;
  if (e < EE) atomicAdd(&rowptr[ei[EE+e]+1], 1);
}

__global__ __launch_bounds__(1024) void scan_kernel(
    int* __restrict__ rowptr, int* __restrict__ cursor)
{
  __shared__ int part[1024];
  const int t = threadIdx.x;
  const int SEG = 16;
  const int base = t*SEG;
  int a[SEG];
  int run = 0;
  #pragma unroll
  for (int i=0;i<SEG;i++){
    int idx = base+i;
    int v = (idx <= NN) ? rowptr[idx] : 0;
    run += v; a[i] = run;
  }
  part[t] = run;
  __syncthreads();
  for (int off=1; off<1024; off<<=1){
    int v = (t>=off) ? part[t-off] : 0;
    __syncthreads();
    part[t] += v;
    __syncthreads();
  }
  int offset = (t>0) ? part[t-1] : 0;
  #pragma unroll
  for (int i=0;i<SEG;i++){
    int idx = base+i;
    if (idx <= NN){
      int val = offset + a[i];
      rowptr[idx] = val;
      if (idx < NN) cursor[idx] = val;
    }
  }
}

__global__ __launch_bounds__(256) void scatter_kernel(
    const int* __restrict__ ei, int* __restrict__ cursor, int* __restrict__ sorted)
{
  int e = blockIdx.x*256 + threadIdx.x;
  if (e < EE){
    int d = ei[EE+e];
    int p = atomicAdd(&cursor[d], 1);
    sorted[p] = e;
  }
}

// ---------------- node k-sort: 64-aligned segments per species ----------------
__global__ void kscan_kernel(const int* __restrict__ khist, int* __restrict__ kcursor)
{
  if (threadIdx.x==0 && blockIdx.x==0){
    int off=0;
    for (int k=0;k<KK;k++){
      kcursor[k]=off;
      off += ((khist[k]+63)>>6)<<6;
    }
  }
}

__global__ __launch_bounds__(256) void kscatter_kernel(
    const int* __restrict__ kidx, int* __restrict__ kcursor, int* __restrict__ nsorted)
{
  int n = blockIdx.x*256 + threadIdx.x;
  if (n < NN){
    int p = atomicAdd(&kcursor[kidx[n]], 1);
    nsorted[p] = n;
  }
}

// ---------------- fused MFMA edge kernel: block-cooperative 64-edge windows ----------------
__global__ __launch_bounds__(256, 2) void edge_kernel(
    const float* __restrict__ pos, const float* __restrict__ shifts,
    const float* __restrict__ Wr1, const float* __restrict__ Wr2,
    const float* __restrict__ Wr3, const float* __restrict__ up,
    const int* __restrict__ ei, const int* __restrict__ sorted,
    float* __restrict__ agg)
{
  __shared__ alignas(16) short sW3T[SHCC*RHH];      // 36864 B
  __shared__ alignas(16) short sW2T[RHH*RHH];       // 8192 B
  __shared__ alignas(16) float sW1T[RHH*NBB];       // 2048 B
  __shared__ alignas(16) char  uni[64*65*4];        // 16640 B: msg | {ef, h2s}
  __shared__ alignas(16) float sh_l[4][16*12];      // 3072 B
  __shared__ int dst_l[64];                         // 256 B

  for (int i=threadIdx.x; i<RHH*SHCC; i+=256){
    int kk = i/SHCC, o = i - kk*SHCC;
    sW3T[(o*RHH + kk) ^ ((o&7)<<3)] = bf16rne(Wr3[i]);
  }
  for (int i=threadIdx.x; i<RHH*RHH; i+=256){
    int k = i>>6, kk = i&63;
    sW2T[(kk*RHH + k) ^ ((kk&7)<<3)] = bf16rne(Wr2[i]);
  }
  for (int i=threadIdx.x; i<NBB*RHH; i+=256){
    int b = i>>6, k = i&63;
    sW1T[k*NBB + b] = Wr1[i];
  }
  __syncthreads();

  const int tid  = threadIdx.x;
  const int lane = tid & 63;
  const int el   = lane & 15;
  const int r    = lane >> 4;
  const int wv   = tid >> 6;
  float* msg = (float*)uni;
  float* efw = (float*)(uni + wv*512);
  short* h2w = (short*)(uni + 2048 + wv*2304);
  float* shw = sh_l[wv];
  const f32x4 zf = {0.f,0.f,0.f,0.f};
  const float PI_ = 3.14159265358979323846f;

  for (int w = blockIdx.x; w < EE/64; w += gridDim.x) {
    const int e0 = w*64 + wv*16;
    {
      const int e = sorted[e0 + el];
      const int src = ei[e], dst = ei[EE+e];
      if (r==0) dst_l[wv*16+el] = dst;
      float x = pos[src*3+0]-pos[dst*3+0]+shifts[e*3+0];
      float y = pos[src*3+1]-pos[dst*3+1]+shifts[e*3+1];
      float z = pos[src*3+2]-pos[dst*3+2]+shifts[e*3+2];
      float rr = sqrtf(x*x+y*y+z*z+1e-12f);
      float ir = 1.0f/rr;
      x*=ir; y*=ir; z*=ir;
      const float S3=1.7320508075688772f, S5h=1.1180339887498949f;
      const float S15=3.872983346207417f, S15h=1.9364916731037085f;
      if (r==0){ shw[el*12+0]=1.0f;            shw[el*12+1]=S3*x;     shw[el*12+2]=S3*y; }
      else if (r==1){ shw[el*12+3]=S3*z;       shw[el*12+4]=S15*x*y;  shw[el*12+5]=S15*y*z; }
      else if (r==2){ shw[el*12+6]=S5h*(3.0f*z*z-1.0f); shw[el*12+7]=S15*x*z; shw[el*12+8]=S15h*(x*x-y*y); }
      float u = rr*0.2f;
      float u2=u*u, u3=u2*u, u6=u3*u3;
      float env = 1.0f - 28.0f*u6 + 48.0f*u6*u - 21.0f*u6*u2;
      env = (u<1.0f)? env : 0.0f;
      env *= ir * 0.6324555320336759f;
      float n1 = (float)(r+1), n2 = (float)(r+5);
      efw[el*8 + r]     = __sinf(n1*PI_*u)*env;
      efw[el*8 + r + 4] = __sinf(n2*PI_*u)*env;
    }
    float h1v[16];
    {
      f32x4 efa = *(const f32x4*)&efw[el*8];
      f32x4 efb = *(const f32x4*)&efw[el*8+4];
      #pragma unroll
      for (int s=0;s<2;s++){
        #pragma unroll
        for (int j=0;j<8;j++){
          int kq = 32*s + 8*r + j;
          f32x4 wa = *(const f32x4*)&sW1T[kq*NBB];
          f32x4 wb = *(const f32x4*)&sW1T[kq*NBB+4];
          float acc = efa[0]*wa[0]+efa[1]*wa[1]+efa[2]*wa[2]+efa[3]*wa[3]
                    + efb[0]*wb[0]+efb[1]*wb[1]+efb[2]*wb[2]+efb[3]*wb[3];
          h1v[s*8+j] = siluf(acc);
        }
      }
    }
    s8b a1s0, a1s1;
    #pragma unroll
    for (int j=0;j<8;j++){ a1s0[j]=bf16rne(h1v[j]); a1s1[j]=bf16rne(h1v[8+j]); }

    f32x4 aw2[4];
    #pragma unroll
    for (int t=0;t<4;t++){
      int kk = 16*t + el;
      int sw = (kk&7)<<3;
      s8b b0 = *(const s8b*)&sW2T[(kk*RHH + 8*r     ) ^ sw];
      s8b b1 = *(const s8b*)&sW2T[(kk*RHH + 8*r + 32) ^ sw];
      f32x4 acc = __builtin_amdgcn_mfma_f32_16x16x32_bf16(a1s0, b0, zf, 0,0,0);
      aw2[t]    = __builtin_amdgcn_mfma_f32_16x16x32_bf16(a1s1, b1, acc, 0,0,0);
    }
    #pragma unroll
    for (int t=0;t<4;t++){
      #pragma unroll
      for (int reg=0;reg<4;reg++)
        h2w[(4*r+reg)*72 + 16*t + el] = bf16rne(siluf(aw2[t][reg]));
    }
    s8b a2s0 = *(const s8b*)&h2w[el*72 + 8*r];
    s8b a2s1 = *(const s8b*)&h2w[el*72 + 32 + 8*r];

    float upv[4][2];
    #pragma unroll
    for (int reg=0;reg<4;reg++){
      int ee = sorted[e0 + 4*r + reg];
      int s_ = ei[ee];
      upv[reg][0] = up[s_*CC + el];
      upv[reg][1] = up[s_*CC + 16 + el];
    }
    __syncthreads();

    unsigned long long runmask;
    {
      bool flag = (lane==0) || (dst_l[lane] != dst_l[lane-1]);
      runmask = __ballot(flag);
    }

    #pragma unroll
    for (int c=0;c<5;c++){
      const int tBeg = 4*c;
      const int tEnd = (c<4)? (tBeg+4) : 18;
      for (int t=tBeg;t<tEnd;t++){
        int o = 16*t + el;
        int sw = (o&7)<<3;
        s8b b0 = *(const s8b*)&sW3T[(o*RHH + 8*r     ) ^ sw];
        s8b b1 = *(const s8b*)&sW3T[(o*RHH + 8*r + 32) ^ sw];
        f32x4 acc = __builtin_amdgcn_mfma_f32_16x16x32_bf16(a2s0, b0, zf, 0,0,0);
        acc       = __builtin_amdgcn_mfma_f32_16x16x32_bf16(a2s1, b1, acc, 0,0,0);
        const int sidx = t>>1, spar = t&1;
        #pragma unroll
        for (int reg=0;reg<4;reg++){
          float v = acc[reg] * shw[(4*r+reg)*12 + sidx] * upv[reg][spar];
          msg[(wv*16 + 4*r + reg)*65 + 16*(t-tBeg) + el] = v;
        }
      }
      __syncthreads();
      {
        const int col = (c<4) ? (tid & 63) : (tid & 31);
        const bool act = (c<4) || ((tid & 63) < 32);
        const int q = tid >> 6;
        const int obase = 64*c;
        if (act){
          unsigned long long m = runmask;
          int j = 0;
          while (m){
            int s = __builtin_ctzll(m);
            m &= (m-1);
            int en = m ? __builtin_ctzll(m) : 64;
            if ((j & 3) == q){
              float a = 0.0f;
              for (int i=s;i<en;i++) a += msg[i*65 + col];
              atomicAdd(agg + (size_t)dst_l[s]*SHCC + obase + col, a);
            }
            j++;
          }
        }
      }
      __syncthreads();
    }
  }
}

// ---------------- node v4: k-sorted 64-node blocks; ONLY core weights in LDS ----------------
// v1 body (known 80-VGPR) + LDS-staged Wprod/Wsc/Wc (padded, conflict-free).
// Staging loops unroll-disabled (v2's VGPR=240 suspect). Act reads stay direct
// (uniform per 32-lane group). All cross-lane comm intra-wave -> no barriers
// after staging.
__global__ __launch_bounds__(256) void node_kernel(
    const float* __restrict__ feats, float* __restrict__ fout,
    const float* __restrict__ agg,
    const int* __restrict__ nsorted, const int* __restrict__ kidx,
    const int* __restrict__ batch,
    const float* __restrict__ Wsc, const float* __restrict__ Wprod,
    const float* __restrict__ WcL,
    const float* __restrict__ We1, const float* __restrict__ We2,
    const float* __restrict__ Wi1, const float* __restrict__ Wi2,
    const float* __restrict__ Wdp, const float* __restrict__ Wup1,
    float* __restrict__ up,
    float* __restrict__ eng, float* __restrict__ inv, float* __restrict__ dip)
{
  __shared__ float sWp[3][32*33];   // 12.7 KB
  __shared__ float sWs[3][32*33];   // 12.7 KB
  __shared__ float sWc[3][32*33];   // 12.7 KB
  __shared__ float s0l[8][CC];
  __shared__ float sul[8][CC];
  __shared__ float vl[8][3][CC];
  __shared__ float hl[8][CC];

  const int base = blockIdx.x*64;
  const int node0 = nsorted[base];
  if (node0 < 0) return;            // whole block is padding (suffix)
  const int kb = kidx[node0];

  #pragma clang loop unroll(disable)
  for (int i=threadIdx.x; i<3*1024; i+=256){
    int lv=i>>10, j=i&1023, c=j>>5, dd=j&31;
    sWp[lv][c*33+dd] = Wprod[i];
    sWs[lv][c*33+dd] = Wsc[(size_t)(kb*3+lv)*1024 + j];
    sWc[lv][c*33+dd] = WcL[(size_t)(lv*KK+kb)*1024 + j];
  }
  __syncthreads();

  const int t=threadIdx.x, nn=t>>5, d=t&31;
  const int LV[SHH] = {0,1,1,1,2,2,2,2,2};

  for (int p=0;p<8;p++){
    const int n = nsorted[base + p*8 + nn];
    const int m = (n>=0) ? n : node0;
    const int b = (n>=0) ? batch[n] : 0;
    const float* ag  = agg   + (size_t)m*SHCC;
    const float* fin = feats + (size_t)m*SHCC;
    float nw[SHH];
    #pragma unroll
    for (int s=0;s<SHH;s++){
      const int lv = LV[s];
      const float* wp = &sWp[lv][d];
      const float* ws = &sWs[lv][d];
      float acc = 0.0f;
      #pragma unroll
      for (int c=0;c<CC;c++)
        acc += ag[s*CC+c]*wp[c*33] + fin[s*CC+c]*ws[c*33];
      nw[s] = acc;
    }
    s0l[nn][d] = nw[0];
    vl[nn][0][d] = nw[1]; vl[nn][1][d] = nw[2]; vl[nn][2][d] = nw[3];
    // intra-wave LDS write->read; no barrier needed (group-private rows)
    float corr = 0.0f;
    {
      const float* wc0 = &sWc[0][d];
      const float* wc1 = &sWc[1][d];
      const float* wc2 = &sWc[2][d];
      #pragma unroll
      for (int c=0;c<CC;c++){
        float s0 = s0l[nn][c];
        float s2 = s0*s0;
        corr += s0*wc0[c*33] + s2*wc1[c*33] + s2*s0*wc2[c*33];
      }
    }
    float su = nw[0] + corr;
    sul[nn][d] = su;
    if (n>=0){
      float* fo = fout + (size_t)n*SHCC;
      fo[d] = su;
      #pragma unroll
      for (int s=1;s<SHH;s++) fo[s*CC+d] = nw[s];
    }
    {
      const int mm = d & 15;
      const float* W = (d < MHH) ? We1 : Wi1;
      float acc = 0.0f;
      #pragma unroll
      for (int c=0;c<CC;c++) acc += sul[nn][c]*W[c*MHH+mm];
      hl[nn][d] = siluf(acc);
    }
    if (n>=0){
      float acc = 0.0f;
      #pragma unroll
      for (int c=0;c<CC;c++) acc += sul[nn][c]*Wup1[c*CC+d];
      up[n*CC+d] = acc * 0.0625f;
    }
    if (n>=0){
      if (d < NEE){
        float acc=0.0f;
        #pragma unroll
        for (int mm=0;mm<MHH;mm++) acc += hl[nn][mm]*We2[mm*NEE+d];
        atomicAdd(&eng[b*NEE+d], acc);
      } else if (d < NEE+NPP){
        const int pp = d-NEE;
        float acc=0.0f;
        #pragma unroll
        for (int mm=0;mm<MHH;mm++) acc += hl[nn][MHH+mm]*Wi2[mm*NPP+pp];
        atomicAdd(&inv[b*NPP+pp], acc);
      } else if (d < 7+3*NDD){
        const int idx = d-7;
        const int v = idx/NDD;
        const int dd = idx - v*NDD;
        float acc=0.0f;
        #pragma unroll
        for (int c=0;c<CC;c++) acc += vl[nn][v][c]*Wdp[c*NDD+dd];
        atomicAdd(&dip[(b*3+v)*NDD+dd], acc);
      }
    }
  }
}

// ---------------- final decode ----------------
__global__ __launch_bounds__(64) void final_kernel(
    const float* __restrict__ eng, const float* __restrict__ inv,
    const float* __restrict__ dip, const float* __restrict__ e0g,
    const float* __restrict__ Wd1, const float* __restrict__ bd1,
    const float* __restrict__ Wd2, const float* __restrict__ bd2,
    float* __restrict__ out)
{
  const int g = threadIdx.x;
  if (g >= GG) return;
  float e0 = e0g[g];
  float iv0=inv[g*NPP+0], iv1=inv[g*NPP+1], iv2=inv[g*NPP+2], iv3=inv[g*NPP+3];
  float o0=bd2[0], o1=bd2[1], o2=bd2[2];
  for (int m=0;m<RHH;m++){
    float hm = bd1[m] + iv0*Wd1[0*RHH+m] + iv1*Wd1[1*RHH+m] + iv2*Wd1[2*RHH+m] + iv3*Wd1[3*RHH+m];
    hm = siluf(hm);
    o0 += hm*Wd2[m*NEE+0]; o1 += hm*Wd2[m*NEE+1]; o2 += hm*Wd2[m*NEE+2];
  }
  float* og = out + g*24;
  og[0]=o0+e0; og[1]=o1+e0; og[2]=o2+e0;
  og[3]=eng[g*NEE+0]+e0; og[4]=eng[g*NEE+1]+e0; og[5]=eng[g*NEE+2]+e0;
  for (int dd=0;dd<NDD;dd++)
    for (int v=0;v<3;v++)
      og[6+dd*3+v] = dip[(g*3+v)*NDD+dd];
}

extern "C" void kernel_launch(void* const* d_in, const int* in_sizes, int n_in,
                              void* d_out, int out_size, void* d_ws, size_t ws_size,
                              hipStream_t stream)
{
  const float* pos    = (const float*)d_in[0];
  const float* attrs  = (const float*)d_in[1];
  const float* shifts = (const float*)d_in[2];
  const float* E0v    = (const float*)d_in[3];
  const float* Wemb   = (const float*)d_in[4];
  const float* Wup    = (const float*)d_in[5];
  const float* Wr1    = (const float*)d_in[6];
  const float* Wr2    = (const float*)d_in[7];
  const float* Wr3    = (const float*)d_in[8];
  const float* Wsc    = (const float*)d_in[9];
  const float* Wprod  = (const float*)d_in[10];
  const float* Wc     = (const float*)d_in[11];
  const float* We1    = (const float*)d_in[12];
  const float* We2    = (const float*)d_in[13];
  const float* Wi1    = (const float*)d_in[14];
  const float* Wi2    = (const float*)d_in[15];
  const float* Wdp    = (const float*)d_in[16];
  const float* Wd1    = (const float*)d_in[17];
  const float* bd1    = (const float*)d_in[18];
  const float* Wd2    = (const float*)d_in[19];
  const float* bd2    = (const float*)d_in[20];
  const int*   ei     = (const int*)d_in[21];
  const int*   batch  = (const int*)d_in[22];
  float* out = (float*)d_out;

  float* feats = (float*)d_ws;                 // N*288
  float* agg   = feats + (size_t)NN*SHCC;      // N*288
  float* up    = agg   + (size_t)NN*SHCC;      // N*32
  float* accum = up    + (size_t)NN*CC;        // 1664 floats + khist
  float* e0g = accum;          // 64
  float* eng = accum + 64;     // 64*3
  float* inv = accum + 256;    // 64*4
  float* dip = accum + 512;    // 64*18
  int*   khist   = (int*)(accum + 1664);       // 16
  int*   kcursor = khist + 16;                 // 16
  int*   kidx    = kcursor + 16;               // NN
  int*   rowptr  = kidx + NN;                  // NN+1
  int*   cursor  = rowptr + NN + 1;            // NN
  int*   sorted  = cursor + NN;                // EE
  int*   nsorted = sorted + EE;                // NPADN

  hipMemsetAsync(accum, 0, (1664+16)*sizeof(float), stream);
  hipMemsetAsync(rowptr, 0, (NN+1)*sizeof(int), stream);
  hipMemsetAsync(nsorted, 0xFF, NPADN*sizeof(int), stream);
  init_kernel<<<(NN*CC)/256, 256, 0, stream>>>(attrs, E0v, Wemb, Wup, batch, kidx, feats, e0g, up, khist);
  hist_kernel<<<EE/256, 256, 0, stream>>>(ei, rowptr);
  scan_kernel<<<1, 1024, 0, stream>>>(rowptr, cursor);
  scatter_kernel<<<EE/256, 256, 0, stream>>>(ei, cursor, sorted);
  kscan_kernel<<<1, 64, 0, stream>>>(khist, kcursor);
  kscatter_kernel<<<(NN+255)/256, 256, 0, stream>>>(kidx, kcursor, nsorted);

  for (int l=0; l<2; ++l){
    hipMemsetAsync(agg, 0, (size_t)NN*SHCC*sizeof(float), stream);
    edge_kernel<<<512, 256, 0, stream>>>(pos, shifts,
        Wr1 + l*NBB*RHH, Wr2 + l*RHH*RHH, Wr3 + l*RHH*SHCC,
        up, ei, sorted, agg);
    node_kernel<<<NBLKN, 256, 0, stream>>>(feats, feats, agg, nsorted, kidx, batch,
        Wsc + l*KK*3*CC*CC, Wprod + l*3*CC*CC, Wc + l*3*KK*CC*CC,
        We1 + l*CC*MHH, We2 + l*MHH*NEE, Wi1 + l*CC*MHH, Wi2 + l*MHH*NPP,
        Wdp + l*CC*NDD, Wup + 1*CC*CC, up,
        eng, inv, dip);
  }
  final_kernel<<<1, 64, 0, stream>>>(eng, inv, dip, e0g, Wd1, bd1, Wd2, bd2, out);
}

// Round 11
// 762.978 us; speedup vs baseline: 2.2924x; 1.1822x over previous
//
#include <hip/hip_runtime.h>
#include <math.h>

#define NN 16000
#define EE 256000
#define GG 64
#define KK 10
#define CC 32
#define NBB 8
#define MHH 16
#define NPP 4
#define NEE 3
#define NDD 6
#define SHH 9
#define RHH 64
#define SHCC (SHH*CC)   // 288

typedef __attribute__((ext_vector_type(8))) short s8b;    // bf16 frag (4 VGPR)
typedef __attribute__((ext_vector_type(4))) float f32x4;  // acc frag

__device__ __forceinline__ float siluf(float x){ return x / (1.0f + __expf(-x)); }
__device__ __forceinline__ short bf16rne(float x){
  unsigned u = __float_as_uint(x);
  unsigned r = u + 0x7FFFu + ((u>>16)&1u);
  return (short)(r>>16);
}

// ---------------- init: kidx, feats0, e0, up(l=0) ----------------
__global__ __launch_bounds__(256) void init_kernel(
    const float* __restrict__ attrs, const float* __restrict__ E0v,
    const float* __restrict__ Wemb, const float* __restrict__ Wup0,
    const int* __restrict__ batch,
    int* __restrict__ kidx, float* __restrict__ feats, float* __restrict__ e0g,
    float* __restrict__ up)
{
  int t = blockIdx.x*blockDim.x + threadIdx.x;
  if (t >= NN*CC) return;
  int n = t >> 5, d = t & 31;
  const float* a = attrs + n*KK;
  int k = 0; float best = a[0];
  #pragma unroll
  for (int j=1;j<KK;j++){ float v=a[j]; if (v>best){best=v;k=j;} }
  float* f = feats + n*SHCC;
  f[d] = Wemb[k*CC+d];
  #pragma unroll
  for (int s=1;s<SHH;s++) f[s*CC+d] = 0.0f;
  float accu = 0.0f;
  #pragma unroll
  for (int c=0;c<CC;c++) accu += Wemb[k*CC+c]*Wup0[c*CC+d];
  up[n*CC+d] = accu * 0.0625f;
  if (d==0){
    kidx[n]=k;
    atomicAdd(&e0g[batch[n]], E0v[k]);
  }
}

// ---------------- counting sort of edges by dst ----------------
__global__ __launch_bounds__(256) void hist_kernel(
    const int* __restrict__ ei, int* __restrict__ rowptr)
{
  int e = blockIdx.x*256 + threadIdx.x;
  if (e < EE) atomicAdd(&rowptr[ei[EE+e]+1], 1);
}

__global__ __launch_bounds__(1024) void scan_kernel(
    int* __restrict__ rowptr, int* __restrict__ cursor)
{
  __shared__ int part[1024];
  const int t = threadIdx.x;
  const int SEG = 16;
  const int base = t*SEG;
  int a[SEG];
  int run = 0;
  #pragma unroll
  for (int i=0;i<SEG;i++){
    int idx = base+i;
    int v = (idx <= NN) ? rowptr[idx] : 0;
    run += v; a[i] = run;
  }
  part[t] = run;
  __syncthreads();
  for (int off=1; off<1024; off<<=1){
    int v = (t>=off) ? part[t-off] : 0;
    __syncthreads();
    part[t] += v;
    __syncthreads();
  }
  int offset = (t>0) ? part[t-1] : 0;
  #pragma unroll
  for (int i=0;i<SEG;i++){
    int idx = base+i;
    if (idx <= NN){
      int val = offset + a[i];
      rowptr[idx] = val;
      if (idx < NN) cursor[idx] = val;
    }
  }
}

__global__ __launch_bounds__(256) void scatter_kernel(
    const int* __restrict__ ei, int* __restrict__ cursor, int* __restrict__ sorted)
{
  int e = blockIdx.x*256 + threadIdx.x;
  if (e < EE){
    int d = ei[EE+e];
    int p = atomicAdd(&cursor[d], 1);
    sorted[p] = e;
  }
}

// ---------------- fused MFMA edge kernel: block-cooperative 64-edge windows ----------------
__global__ __launch_bounds__(256, 2) void edge_kernel(
    const float* __restrict__ pos, const float* __restrict__ shifts,
    const float* __restrict__ Wr1, const float* __restrict__ Wr2,
    const float* __restrict__ Wr3, const float* __restrict__ up,
    const int* __restrict__ ei, const int* __restrict__ sorted,
    float* __restrict__ agg)
{
  __shared__ alignas(16) short sW3T[SHCC*RHH];      // 36864 B
  __shared__ alignas(16) short sW2T[RHH*RHH];       // 8192 B
  __shared__ alignas(16) float sW1T[RHH*NBB];       // 2048 B
  __shared__ alignas(16) char  uni[64*65*4];        // 16640 B: msg | {ef, h2s}
  __shared__ alignas(16) float sh_l[4][16*12];      // 3072 B
  __shared__ int dst_l[64];                         // 256 B

  for (int i=threadIdx.x; i<RHH*SHCC; i+=256){
    int kk = i/SHCC, o = i - kk*SHCC;
    sW3T[(o*RHH + kk) ^ ((o&7)<<3)] = bf16rne(Wr3[i]);
  }
  for (int i=threadIdx.x; i<RHH*RHH; i+=256){
    int k = i>>6, kk = i&63;
    sW2T[(kk*RHH + k) ^ ((kk&7)<<3)] = bf16rne(Wr2[i]);
  }
  for (int i=threadIdx.x; i<NBB*RHH; i+=256){
    int b = i>>6, k = i&63;
    sW1T[k*NBB + b] = Wr1[i];
  }
  __syncthreads();

  const int tid  = threadIdx.x;
  const int lane = tid & 63;
  const int el   = lane & 15;
  const int r    = lane >> 4;
  const int wv   = tid >> 6;
  float* msg = (float*)uni;
  float* efw = (float*)(uni + wv*512);
  short* h2w = (short*)(uni + 2048 + wv*2304);
  float* shw = sh_l[wv];
  const f32x4 zf = {0.f,0.f,0.f,0.f};
  const float PI_ = 3.14159265358979323846f;

  for (int w = blockIdx.x; w < EE/64; w += gridDim.x) {
    const int e0 = w*64 + wv*16;
    {
      const int e = sorted[e0 + el];
      const int src = ei[e], dst = ei[EE+e];
      if (r==0) dst_l[wv*16+el] = dst;
      float x = pos[src*3+0]-pos[dst*3+0]+shifts[e*3+0];
      float y = pos[src*3+1]-pos[dst*3+1]+shifts[e*3+1];
      float z = pos[src*3+2]-pos[dst*3+2]+shifts[e*3+2];
      float rr = sqrtf(x*x+y*y+z*z+1e-12f);
      float ir = 1.0f/rr;
      x*=ir; y*=ir; z*=ir;
      const float S3=1.7320508075688772f, S5h=1.1180339887498949f;
      const float S15=3.872983346207417f, S15h=1.9364916731037085f;
      if (r==0){ shw[el*12+0]=1.0f;            shw[el*12+1]=S3*x;     shw[el*12+2]=S3*y; }
      else if (r==1){ shw[el*12+3]=S3*z;       shw[el*12+4]=S15*x*y;  shw[el*12+5]=S15*y*z; }
      else if (r==2){ shw[el*12+6]=S5h*(3.0f*z*z-1.0f); shw[el*12+7]=S15*x*z; shw[el*12+8]=S15h*(x*x-y*y); }
      float u = rr*0.2f;
      float u2=u*u, u3=u2*u, u6=u3*u3;
      float env = 1.0f - 28.0f*u6 + 48.0f*u6*u - 21.0f*u6*u2;
      env = (u<1.0f)? env : 0.0f;
      env *= ir * 0.6324555320336759f;
      float n1 = (float)(r+1), n2 = (float)(r+5);
      efw[el*8 + r]     = __sinf(n1*PI_*u)*env;
      efw[el*8 + r + 4] = __sinf(n2*PI_*u)*env;
    }
    float h1v[16];
    {
      f32x4 efa = *(const f32x4*)&efw[el*8];
      f32x4 efb = *(const f32x4*)&efw[el*8+4];
      #pragma unroll
      for (int s=0;s<2;s++){
        #pragma unroll
        for (int j=0;j<8;j++){
          int kq = 32*s + 8*r + j;
          f32x4 wa = *(const f32x4*)&sW1T[kq*NBB];
          f32x4 wb = *(const f32x4*)&sW1T[kq*NBB+4];
          float acc = efa[0]*wa[0]+efa[1]*wa[1]+efa[2]*wa[2]+efa[3]*wa[3]
                    + efb[0]*wb[0]+efb[1]*wb[1]+efb[2]*wb[2]+efb[3]*wb[3];
          h1v[s*8+j] = siluf(acc);
        }
      }
    }
    s8b a1s0, a1s1;
    #pragma unroll
    for (int j=0;j<8;j++){ a1s0[j]=bf16rne(h1v[j]); a1s1[j]=bf16rne(h1v[8+j]); }

    f32x4 aw2[4];
    #pragma unroll
    for (int t=0;t<4;t++){
      int kk = 16*t + el;
      int sw = (kk&7)<<3;
      s8b b0 = *(const s8b*)&sW2T[(kk*RHH + 8*r     ) ^ sw];
      s8b b1 = *(const s8b*)&sW2T[(kk*RHH + 8*r + 32) ^ sw];
      f32x4 acc = __builtin_amdgcn_mfma_f32_16x16x32_bf16(a1s0, b0, zf, 0,0,0);
      aw2[t]    = __builtin_amdgcn_mfma_f32_16x16x32_bf16(a1s1, b1, acc, 0,0,0);
    }
    #pragma unroll
    for (int t=0;t<4;t++){
      #pragma unroll
      for (int reg=0;reg<4;reg++)
        h2w[(4*r+reg)*72 + 16*t + el] = bf16rne(siluf(aw2[t][reg]));
    }
    s8b a2s0 = *(const s8b*)&h2w[el*72 + 8*r];
    s8b a2s1 = *(const s8b*)&h2w[el*72 + 32 + 8*r];

    float upv[4][2];
    #pragma unroll
    for (int reg=0;reg<4;reg++){
      int ee = sorted[e0 + 4*r + reg];
      int s_ = ei[ee];
      upv[reg][0] = up[s_*CC + el];
      upv[reg][1] = up[s_*CC + 16 + el];
    }
    __syncthreads();   // phase A done; ef/h2 dead; dst_l complete

    unsigned long long runmask;
    {
      bool flag = (lane==0) || (dst_l[lane] != dst_l[lane-1]);
      runmask = __ballot(flag);
    }

    #pragma unroll
    for (int c=0;c<5;c++){
      const int tBeg = 4*c;
      const int tEnd = (c<4)? (tBeg+4) : 18;
      for (int t=tBeg;t<tEnd;t++){
        int o = 16*t + el;
        int sw = (o&7)<<3;
        s8b b0 = *(const s8b*)&sW3T[(o*RHH + 8*r     ) ^ sw];
        s8b b1 = *(const s8b*)&sW3T[(o*RHH + 8*r + 32) ^ sw];
        f32x4 acc = __builtin_amdgcn_mfma_f32_16x16x32_bf16(a2s0, b0, zf, 0,0,0);
        acc       = __builtin_amdgcn_mfma_f32_16x16x32_bf16(a2s1, b1, acc, 0,0,0);
        const int sidx = t>>1, spar = t&1;
        #pragma unroll
        for (int reg=0;reg<4;reg++){
          float v = acc[reg] * shw[(4*r+reg)*12 + sidx] * upv[reg][spar];
          msg[(wv*16 + 4*r + reg)*65 + 16*(t-tBeg) + el] = v;
        }
      }
      __syncthreads();
      {
        const int col = (c<4) ? (tid & 63) : (tid & 31);
        const bool act = (c<4) || ((tid & 63) < 32);
        const int q = tid >> 6;
        const int obase = 64*c;
        if (act){
          unsigned long long m = runmask;
          int j = 0;
          while (m){
            int s = __builtin_ctzll(m);
            m &= (m-1);
            int en = m ? __builtin_ctzll(m) : 64;
            if ((j & 3) == q){
              float a = 0.0f;
              for (int i=s;i<en;i++) a += msg[i*65 + col];
              atomicAdd(agg + (size_t)dst_l[s]*SHCC + obase + col, a);
            }
            j++;
          }
        }
      }
      __syncthreads();
    }
  }
}

// ---------------- node update + readouts + up(l+1) — proven 80-VGPR body ----------------
__global__ __launch_bounds__(256) void node_kernel(
    const float* __restrict__ feats, float* __restrict__ fout,
    const float* __restrict__ agg,
    const int* __restrict__ kidx, const int* __restrict__ batch,
    const float* __restrict__ Wsc, const float* __restrict__ Wprod,
    const float* __restrict__ WcL,
    const float* __restrict__ We1, const float* __restrict__ We2,
    const float* __restrict__ Wi1, const float* __restrict__ Wi2,
    const float* __restrict__ Wdp, const float* __restrict__ Wup1,
    float* __restrict__ up,
    float* __restrict__ eng, float* __restrict__ inv, float* __restrict__ dip)
{
  __shared__ float s0l[8][CC];
  __shared__ float sul[8][CC];
  __shared__ float vl[8][3][CC];
  __shared__ float hl[8][CC];
  const int t = threadIdx.x;
  const int nn = t >> 5;
  const int d = t & 31;
  const int n = blockIdx.x*8 + nn;
  const int k = kidx[n];
  const int b = batch[n];
  const float* fin = feats + n*SHCC;
  const float* ag = agg + n*SHCC;
  float nw[SHH];
  const int LV[SHH] = {0,1,1,1,2,2,2,2,2};
  #pragma unroll
  for (int s=0;s<SHH;s++){
    const int lv = LV[s];
    const float* wp  = Wprod + lv*CC*CC + d;
    const float* wsc = Wsc + (k*3+lv)*CC*CC + d;
    float acc = 0.0f;
    #pragma unroll
    for (int c=0;c<CC;c++)
      acc += ag[s*CC+c]*wp[c*CC] + fin[s*CC+c]*wsc[c*CC];
    nw[s] = acc;
  }
  s0l[nn][d] = nw[0];
  vl[nn][0][d] = nw[1]; vl[nn][1][d] = nw[2]; vl[nn][2][d] = nw[3];
  __syncthreads();
  float corr = 0.0f;
  {
    const float* wc0 = WcL + (0*KK+k)*CC*CC + d;
    const float* wc1 = WcL + (1*KK+k)*CC*CC + d;
    const float* wc2 = WcL + (2*KK+k)*CC*CC + d;
    #pragma unroll
    for (int c=0;c<CC;c++){
      float s0 = s0l[nn][c];
      float s2 = s0*s0;
      corr += s0*wc0[c*CC] + s2*wc1[c*CC] + s2*s0*wc2[c*CC];
    }
  }
  float su = nw[0] + corr;
  sul[nn][d] = su;
  float* fo = fout + n*SHCC;
  fo[d] = su;
  #pragma unroll
  for (int s=1;s<SHH;s++) fo[s*CC+d] = nw[s];
  __syncthreads();
  {
    const int m = d & 15;
    const float* W = (d < MHH) ? We1 : Wi1;
    float acc = 0.0f;
    #pragma unroll
    for (int c=0;c<CC;c++) acc += sul[nn][c]*W[c*MHH+m];
    hl[nn][d] = siluf(acc);
  }
  // up for next layer (folded /AVG_NBR)
  {
    float acc = 0.0f;
    #pragma unroll
    for (int c=0;c<CC;c++) acc += sul[nn][c]*Wup1[c*CC+d];
    up[n*CC+d] = acc * 0.0625f;
  }
  __syncthreads();
  if (d < NEE){
    float acc=0.0f;
    #pragma unroll
    for (int m=0;m<MHH;m++) acc += hl[nn][m]*We2[m*NEE+d];
    atomicAdd(&eng[b*NEE+d], acc);
  } else if (d < NEE+NPP){
    const int p = d-NEE;
    float acc=0.0f;
    #pragma unroll
    for (int m=0;m<MHH;m++) acc += hl[nn][MHH+m]*Wi2[m*NPP+p];
    atomicAdd(&inv[b*NPP+p], acc);
  } else if (d < 7+3*NDD){
    const int idx = d-7;
    const int v = idx/NDD;
    const int dd = idx - v*NDD;
    float acc=0.0f;
    #pragma unroll
    for (int c=0;c<CC;c++) acc += vl[nn][v][c]*Wdp[c*NDD+dd];
    atomicAdd(&dip[(b*3+v)*NDD+dd], acc);
  }
}

// ---------------- final decode ----------------
__global__ __launch_bounds__(64) void final_kernel(
    const float* __restrict__ eng, const float* __restrict__ inv,
    const float* __restrict__ dip, const float* __restrict__ e0g,
    const float* __restrict__ Wd1, const float* __restrict__ bd1,
    const float* __restrict__ Wd2, const float* __restrict__ bd2,
    float* __restrict__ out)
{
  const int g = threadIdx.x;
  if (g >= GG) return;
  float e0 = e0g[g];
  float iv0=inv[g*NPP+0], iv1=inv[g*NPP+1], iv2=inv[g*NPP+2], iv3=inv[g*NPP+3];
  float o0=bd2[0], o1=bd2[1], o2=bd2[2];
  for (int m=0;m<RHH;m++){
    float hm = bd1[m] + iv0*Wd1[0*RHH+m] + iv1*Wd1[1*RHH+m] + iv2*Wd1[2*RHH+m] + iv3*Wd1[3*RHH+m];
    hm = siluf(hm);
    o0 += hm*Wd2[m*NEE+0]; o1 += hm*Wd2[m*NEE+1]; o2 += hm*Wd2[m*NEE+2];
  }
  float* og = out + g*24;
  og[0]=o0+e0; og[1]=o1+e0; og[2]=o2+e0;
  og[3]=eng[g*NEE+0]+e0; og[4]=eng[g*NEE+1]+e0; og[5]=eng[g*NEE+2]+e0;
  for (int dd=0;dd<NDD;dd++)
    for (int v=0;v<3;v++)
      og[6+dd*3+v] = dip[(g*3+v)*NDD+dd];
}

extern "C" void kernel_launch(void* const* d_in, const int* in_sizes, int n_in,
                              void* d_out, int out_size, void* d_ws, size_t ws_size,
                              hipStream_t stream)
{
  const float* pos    = (const float*)d_in[0];
  const float* attrs  = (const float*)d_in[1];
  const float* shifts = (const float*)d_in[2];
  const float* E0v    = (const float*)d_in[3];
  const float* Wemb   = (const float*)d_in[4];
  const float* Wup    = (const float*)d_in[5];
  const float* Wr1    = (const float*)d_in[6];
  const float* Wr2    = (const float*)d_in[7];
  const float* Wr3    = (const float*)d_in[8];
  const float* Wsc    = (const float*)d_in[9];
  const float* Wprod  = (const float*)d_in[10];
  const float* Wc     = (const float*)d_in[11];
  const float* We1    = (const float*)d_in[12];
  const float* We2    = (const float*)d_in[13];
  const float* Wi1    = (const float*)d_in[14];
  const float* Wi2    = (const float*)d_in[15];
  const float* Wdp    = (const float*)d_in[16];
  const float* Wd1    = (const float*)d_in[17];
  const float* bd1    = (const float*)d_in[18];
  const float* Wd2    = (const float*)d_in[19];
  const float* bd2    = (const float*)d_in[20];
  const int*   ei     = (const int*)d_in[21];
  const int*   batch  = (const int*)d_in[22];
  float* out = (float*)d_out;

  float* feats = (float*)d_ws;                 // N*288
  float* agg   = feats + (size_t)NN*SHCC;      // N*288
  float* up    = agg   + (size_t)NN*SHCC;      // N*32
  float* accum = up    + (size_t)NN*CC;        // 1664 floats
  float* e0g = accum;          // 64
  float* eng = accum + 64;     // 64*3
  float* inv = accum + 256;    // 64*4
  float* dip = accum + 512;    // 64*18
  int*   kidx   = (int*)(accum + 1664);        // N ints
  int*   rowptr = kidx + NN;                   // NN+1 ints
  int*   cursor = rowptr + NN + 1;             // NN ints
  int*   sorted = cursor + NN;                 // EE ints

  hipMemsetAsync(accum, 0, 1664*sizeof(float), stream);
  hipMemsetAsync(rowptr, 0, (NN+1)*sizeof(int), stream);
  init_kernel<<<(NN*CC)/256, 256, 0, stream>>>(attrs, E0v, Wemb, Wup, batch, kidx, feats, e0g, up);
  hist_kernel<<<EE/256, 256, 0, stream>>>(ei, rowptr);
  scan_kernel<<<1, 1024, 0, stream>>>(rowptr, cursor);
  scatter_kernel<<<EE/256, 256, 0, stream>>>(ei, cursor, sorted);

  for (int l=0; l<2; ++l){
    hipMemsetAsync(agg, 0, (size_t)NN*SHCC*sizeof(float), stream);
    edge_kernel<<<512, 256, 0, stream>>>(pos, shifts,
        Wr1 + l*NBB*RHH, Wr2 + l*RHH*RHH, Wr3 + l*RHH*SHCC,
        up, ei, sorted, agg);
    node_kernel<<<NN/8, 256, 0, stream>>>(feats, feats, agg, kidx, batch,
        Wsc + l*KK*3*CC*CC, Wprod + l*3*CC*CC, Wc + l*3*KK*CC*CC,
        We1 + l*CC*MHH, We2 + l*MHH*NEE, Wi1 + l*CC*MHH, Wi2 + l*MHH*NPP,
        Wdp + l*CC*NDD, Wup + 1*CC*CC, up,
        eng, inv, dip);
  }
  final_kernel<<<1, 64, 0, stream>>>(eng, inv, dip, e0g, Wd1, bd1, Wd2, bd2, out);
}